// Round 4
// baseline (26.737 us; speedup 1.0000x reference)
//
#include <hip/hip_runtime.h>
#include <math.h>

#define NIMG 16
#define H 512
#define W 512
#define ORI 10
#define TS 35          // LDS row stride for T/U (34 cols + 1 pad; 35%32=3 -> <=2-way)

// ---------------- Kernel 1: per-cell 10-bin HOG histograms ----------------
// tile 64 rows x 32 cols; grid (16,8,16) = 2048 blocks; 256 threads (4 waves).
// Stage vertically-filtered columns T = a+2b+c, U = a-c (split load/store so
// HBM latency is paid once, not per element). 8 threads per cell, 1 pixel row
// each. Register cumulative histogram T[11] via 9 cross-product sign tests.
__global__ __launch_bounds__(256, 8) void hog_cells_k(const float* __restrict__ img,
                                                      float* __restrict__ cells) {
    __shared__ float Tl[64 * TS];
    __shared__ float Ul[64 * TS];
    __shared__ float hist[32 * 11];
    const int n = blockIdx.z;
    const int ty0 = blockIdx.y * 64;
    const int tx0 = blockIdx.x * 32;
    const float* im = img + (size_t)n * (H * W);
    const int tid = threadIdx.x;

    // ---- staging phase A: issue all 27 loads (64x34 elements / 256 threads) ----
    float va[9], vb[9], vc[9];
    int off[9];
    #pragma unroll
    for (int k = 0; k < 9; ++k) {
        int e = tid + k * 256;
        int r = e / 34, c = e - r * 34;        // const-div -> magic mul
        bool ok = (e < 64 * 34);
        int grow = ty0 + r;                    // in [0,511] when ok
        int gcol = tx0 + c - 1;
        bool cin = ok && ((unsigned)gcol < (unsigned)W);
        const float* p = im + (size_t)grow * W + gcol;
        va[k] = (cin && grow >= 1)     ? p[-W] : 0.0f;
        vb[k] =  cin                   ? p[0]  : 0.0f;
        vc[k] = (cin && grow < H - 1)  ? p[W]  : 0.0f;
        off[k] = r * TS + c;
    }
    // ---- staging phase B: filter + LDS store (single latency exposure) ----
    #pragma unroll
    for (int k = 0; k < 9; ++k) {
        int e = tid + k * 256;
        if (e < 64 * 34) {
            Tl[off[k]] = va[k] + 2.0f * vb[k] + vc[k];
            Ul[off[k]] = va[k] - vc[k];
        }
    }
    __syncthreads();

    // ---- per-pixel-row compute ----
    const int cell = tid >> 3;      // 0..31 (8 cell-rows x 4 cell-cols)
    const int sub  = tid & 7;       // pixel row within cell
    const int cy = cell >> 2, cx = cell & 3;
    const int base = (cy * 8 + sub) * TS + cx * 8;  // window col j -> base+j

    float t[10], u[10];
    #pragma unroll
    for (int j = 0; j < 10; ++j) { t[j] = Tl[base + j]; u[j] = Ul[base + j]; }

    float T[11];
    #pragma unroll
    for (int j = 0; j < 11; ++j) T[j] = 0.0f;

    #pragma unroll
    for (int j = 0; j < 8; ++j) {
        float gx = t[j] - t[j+2];                    // T[c-1] - T[c+1]
        float gy = u[j] + 2.0f * u[j+1] + u[j+2];    // U[c-1]+2U[c]+U[c+1]
        float mag = __builtin_amdgcn_sqrtf(gx * gx + gy * gy);
        float wB = 1.0f - mag;
        bool gx0 = (gx == 0.0f);
        bool gy0 = (gy == 0.0f);
        if (gx0 | gy0) wB = 0.0f;        // exact-integer p: floor==ceil, weight 1
        float yv = fabsf(gx);
        float xv = (gx < 0.0f) ? -gy : gy;
        if (gx0) xv = 1.0f;              // all e_j false -> bin0 += 1
        float y1 = yv * 0.9510565163f, y2 = yv * 0.8090169944f,
              y3 = yv * 0.5877852523f, y4 = yv * 0.3090169944f;
        float x1 = xv * 0.3090169944f, x2 = xv * 0.5877852523f,
              x3 = xv * 0.8090169944f, x4 = xv * 0.9510565163f;
        bool e1 = (y1 >= x1), e2 = (y2 >= x2), e3 = (y3 >= x3), e4 = (y4 >= x4);
        bool e5 = (xv <= 0.0f);
        bool e6 = (y4 <= -x4), e7 = (y3 <= -x3), e8 = (y2 <= -x2), e9 = (y1 <= -x1);
        // cumulative histogram: slots <= bin get 1 (=mag+wB), slot bin+1 gets wB
        T[0]  += 1.0f;
        T[1]  += e1 ? 1.0f : wB;
        T[2]  += e2 ? 1.0f : (e1 ? wB : 0.0f);
        T[3]  += e3 ? 1.0f : (e2 ? wB : 0.0f);
        T[4]  += e4 ? 1.0f : (e3 ? wB : 0.0f);
        T[5]  += e5 ? 1.0f : (e4 ? wB : 0.0f);
        T[6]  += e6 ? 1.0f : (e5 ? wB : 0.0f);
        T[7]  += e7 ? 1.0f : (e6 ? wB : 0.0f);
        T[8]  += e8 ? 1.0f : (e7 ? wB : 0.0f);
        T[9]  += e9 ? 1.0f : (e8 ? wB : 0.0f);
        T[10] += e9 ? wB : 0.0f;         // ceil wrap: slot10 -> bin0
    }

    // cumulative -> bins; 8-lane shuffle reduce (lanes of a cell are consecutive)
    float b[10];
    #pragma unroll
    for (int j = 0; j < 10; ++j) b[j] = T[j] - T[j + 1];
    b[0] += T[10];
    #pragma unroll
    for (int j = 0; j < 10; ++j) {
        float v = b[j];
        v += __shfl_xor(v, 1);
        v += __shfl_xor(v, 2);
        v += __shfl_xor(v, 4);
        b[j] = v;
    }
    if (sub == 0) {
        #pragma unroll
        for (int j = 0; j < 10; ++j) hist[cell * 11 + j] = b[j];
    }
    __syncthreads();

    // cell means writeout: 320 values per block
    const int gcy0 = blockIdx.y * 8;
    const int gcx0 = blockIdx.x * 4;
    for (int i = tid; i < 32 * ORI; i += 256) {
        int bb = i >> 5;          // 0..9
        int cl = i & 31;
        int cyy = cl >> 2, cxx = cl & 3;
        float v = hist[cl * 11 + bb] * 0.015625f;
        cells[(((size_t)n * ORI + bb) * 64 + gcy0 + cyy) * 64 + (gcx0 + cxx)] = v;
    }
}

// ---------------- Kernel 2: 2x2 block gather + L2 normalize ----------------
__global__ __launch_bounds__(256) void hog_blocks_k(const float* __restrict__ cells,
                                                    float* __restrict__ out) {
    const int total = NIMG * ORI * 63 * 63;
    int idx = blockIdx.x * blockDim.x + threadIdx.x;
    if (idx >= total) return;
    int bc = idx % 63;
    int t  = idx / 63;
    int br = t % 63;
    int no = t / 63;                       // n*ORI + o
    const float* c = cells + (((size_t)no * 64 + br) * 64 + bc);
    float c00 = c[0], c01 = c[1], c10 = c[64], c11 = c[65];
    float s = ((c00 + c01) + (c10 + c11));
    float denom = sqrtf(s * s + 1e-10f);   // sqrt(sum^2 + EPS^2)
    float inv = 1.0f / denom;
    float4 o;
    o.x = c00 * inv;
    o.y = c01 * inv;
    o.z = c10 * inv;
    o.w = c11 * inv;
    reinterpret_cast<float4*>(out)[idx] = o;
}

extern "C" void kernel_launch(void* const* d_in, const int* in_sizes, int n_in,
                              void* d_out, int out_size, void* d_ws, size_t ws_size,
                              hipStream_t stream) {
    (void)in_sizes; (void)n_in; (void)out_size; (void)ws_size;
    const float* img = (const float*)d_in[0];   // (16,1,512,512)
    float* out   = (float*)d_out;               // (16, 10*63*63*2*2) f32
    float* cells = (float*)d_ws;                // (16,10,64,64) f32 scratch

    hog_cells_k<<<dim3(16, 8, NIMG), 256, 0, stream>>>(img, cells);

    const int total = NIMG * ORI * 63 * 63;
    hog_blocks_k<<<(total + 255) / 256, 256, 0, stream>>>(cells, out);
}